// Round 1
// baseline (440.596 us; speedup 1.0000x reference)
//
#include <hip/hip_runtime.h>
#include <cstddef>

static constexpr int Nn = 4096;
static constexpr int Dd = 256;
static constexpr int Ss = 32;
static constexpr int Kk = 4;
static constexpr float kEta   = 0.5f;
static constexpr float kCoeff = 0.03125f; // S/(N*EPS^2) = 32/(4096*0.25)

// ---------------- reduction helpers ----------------
__device__ __forceinline__ float waveReduceSum(float v){
  #pragma unroll
  for (int off = 32; off > 0; off >>= 1) v += __shfl_down(v, off, 64);
  return v;
}
__device__ __forceinline__ float waveReduceMax(float v){
  #pragma unroll
  for (int off = 32; off > 0; off >>= 1) v = fmaxf(v, __shfl_down(v, off, 64));
  return v;
}
__device__ __forceinline__ int waveReduceSumI(int v){
  #pragma unroll
  for (int off = 32; off > 0; off >>= 1) v += __shfl_down(v, off, 64);
  return v;
}

// ---------------- init: zero scalar slots, compute w = softmax(hop_weights) ----------------
__global__ void init_kernel(const float* __restrict__ hw, float* __restrict__ out){
  if (threadIdx.x == 0){
    out[1048576] = 0.f;   // orth_loss
    out[1048577] = 0.f;   // lap_smooth
    float a0=hw[0], a1=hw[1], a2=hw[2], a3=hw[3];
    float m = fmaxf(fmaxf(a0,a1), fmaxf(a2,a3));
    float e0=expf(a0-m), e1=expf(a1-m), e2=expf(a2-m), e3=expf(a3-m);
    float s = e0+e1+e2+e3;
    out[1048578]=e0/s; out[1048579]=e1/s; out[1048580]=e2/s; out[1048581]=e3/s;
  }
}

// ---------------- CSR build: per-row nnz count (A entries are exactly 0.0/1.0) ----------------
__global__ __launch_bounds__(256) void cnt_kernel(const float* __restrict__ A, int* __restrict__ cnt){
  int i = blockIdx.x;
  const float* row = A + (size_t)i * Nn;
  int c = 0;
  for (int j = threadIdx.x; j < Nn; j += 256) c += (row[j] != 0.f) ? 1 : 0;
  c = waveReduceSumI(c);
  __shared__ int red[4];
  if ((threadIdx.x & 63) == 0) red[threadIdx.x >> 6] = c;
  __syncthreads();
  if (threadIdx.x == 0) cnt[i] = red[0]+red[1]+red[2]+red[3];
}

// ---------------- exclusive scan of 4096 counts -> row_ptr ----------------
__global__ __launch_bounds__(1024) void scan_kernel(const int* __restrict__ cnt, int* __restrict__ rowp){
  __shared__ int ls[1024];
  int t = threadIdx.x;
  int l0 = cnt[t*4+0], l1 = cnt[t*4+1], l2 = cnt[t*4+2], l3 = cnt[t*4+3];
  int s = l0+l1+l2+l3;
  ls[t] = s;
  __syncthreads();
  for (int off = 1; off < 1024; off <<= 1){
    int v = (t >= off) ? ls[t-off] : 0;
    __syncthreads();
    ls[t] += v;
    __syncthreads();
  }
  int run = ls[t] - s;      // exclusive prefix
  rowp[t*4+0] = run; run += l0;
  rowp[t*4+1] = run; run += l1;
  rowp[t*4+2] = run; run += l2;
  rowp[t*4+3] = run; run += l3;
  if (t == 1023) rowp[4096] = run;
}

// ---------------- CSR fill (ordered compaction via ballot) ----------------
__global__ __launch_bounds__(256) void fill_kernel(const float* __restrict__ A,
                                                   const int* __restrict__ rowp,
                                                   int* __restrict__ colx){
  int i = blockIdx.x;
  const float* row = A + (size_t)i * Nn;
  __shared__ int wave_cnt[4];
  __shared__ int chunk_base;
  if (threadIdx.x == 0) chunk_base = rowp[i];
  __syncthreads();
  int lane = threadIdx.x & 63;
  int wave = threadIdx.x >> 6;
  for (int c0 = 0; c0 < Nn; c0 += 256){
    int j = c0 + threadIdx.x;
    bool p = (row[j] != 0.f);
    unsigned long long mask = __ballot(p);
    int lp = __popcll(mask & ((1ull << lane) - 1ull));
    int wc = __popcll(mask);
    if (lane == 0) wave_cnt[wave] = wc;
    __syncthreads();
    int wbase = 0;
    for (int ww = 0; ww < wave; ww++) wbase += wave_cnt[ww];
    int total = wave_cnt[0]+wave_cnt[1]+wave_cnt[2]+wave_cnt[3];
    if (p) colx[chunk_base + wbase + lp] = j;
    __syncthreads();
    if (threadIdx.x == 0) chunk_base += total;
    __syncthreads();
  }
}

// ---------------- Z = Uk^T @ hops_k^T : Z (K,S,N) and Zt (K,N,S) ----------------
__global__ __launch_bounds__(256) void z_kernel(const float* __restrict__ hops,
                                                const float* __restrict__ U,
                                                float* __restrict__ Z,
                                                float* __restrict__ Zt){
  int b = blockIdx.x;
  int k = b >> 8;              // 256 blocks per k
  int i0 = (b & 255) * 16;
  __shared__ float Us[Dd*Ss];      // 32 KB, Us[d*32+s]
  __shared__ float hs[16][Dd];     // 16 KB
  __shared__ float vred[8][Ss];
  for (int t = threadIdx.x; t < Dd*Ss; t += 256) Us[t] = U[(size_t)k*Dd*Ss + t];
  for (int t = threadIdx.x; t < 16*Dd; t += 256){
    int ii = t >> 8, d = t & 255;
    hs[ii][d] = hops[((size_t)k*Nn + (i0+ii))*Dd + d];
  }
  __syncthreads();
  int s = threadIdx.x & 31, grp = threadIdx.x >> 5;
  for (int ii = 0; ii < 16; ii++){
    float part = 0.f;
    int dbase = grp * 32;
    #pragma unroll 8
    for (int dt = 0; dt < 32; dt++){
      int d = dbase + dt;
      part += hs[ii][d] * Us[d*32 + s];
    }
    vred[grp][s] = part;
    __syncthreads();
    if (threadIdx.x < 32){
      float acc = 0.f;
      #pragma unroll
      for (int g2 = 0; g2 < 8; g2++) acc += vred[g2][threadIdx.x];
      int i = i0 + ii;
      Z [((size_t)k*Ss + threadIdx.x)*Nn + i] = acc;
      Zt[((size_t)k*Nn + i)*Ss + threadIdx.x] = acc;
    }
    __syncthreads();
  }
}

// ---------------- M = I + coeff * Z Z^T  (per k, 32x32) ----------------
__global__ __launch_bounds__(256) void m_kernel(const float* __restrict__ Z, float* __restrict__ M){
  int g = blockIdx.x;                       // k*1024 + s1*32 + s2
  int k = g >> 10, r = g & 1023, s1 = r >> 5, s2 = r & 31;
  const float* z1 = Z + ((size_t)k*Ss + s1)*Nn;
  const float* z2 = Z + ((size_t)k*Ss + s2)*Nn;
  float acc = 0.f;
  for (int i = threadIdx.x; i < Nn; i += 256) acc += z1[i]*z2[i];
  acc = waveReduceSum(acc);
  __shared__ float red[4];
  if ((threadIdx.x & 63) == 0) red[threadIdx.x >> 6] = acc;
  __syncthreads();
  if (threadIdx.x == 0){
    float t = red[0]+red[1]+red[2]+red[3];
    M[g] = kCoeff * t + ((s1 == s2) ? 1.f : 0.f);
  }
}

// ---------------- 32x32 SPD inverse via Gauss-Jordan (diag ~129, no pivoting needed) ----------------
__global__ __launch_bounds__(1024) void inv_kernel(const float* __restrict__ M, float* __restrict__ Minv){
  int k = blockIdx.x;
  int c = threadIdx.x, r = threadIdx.y;
  __shared__ float a[32][65];
  __shared__ float piv;
  __shared__ float fcol[32];
  a[r][c]      = M[((size_t)k*Ss + r)*Ss + c];
  a[r][32 + c] = (r == c) ? 1.f : 0.f;
  for (int p = 0; p < 32; p++){
    __syncthreads();
    if (c == 0 && r == 0) piv = 1.f / a[p][p];
    __syncthreads();
    if (r == p){ a[p][c] *= piv; a[p][32+c] *= piv; }
    __syncthreads();
    if (c == 0) fcol[r] = a[r][p];
    __syncthreads();
    if (r != p){
      float f = fcol[r];
      a[r][c]    -= f * a[p][c];
      a[r][32+c] -= f * a[p][32+c];
    }
  }
  __syncthreads();
  Minv[((size_t)k*Ss + r)*Ss + c] = a[r][32 + c];
}

// ---------------- MZt (K,N,S): MZt[i][s] = sum_s2 Minv[s][s2] * Zt[i][s2] ----------------
__global__ __launch_bounds__(256) void mz_kernel(const float* __restrict__ Zt,
                                                 const float* __restrict__ Minv,
                                                 float* __restrict__ MZt){
  int b = blockIdx.x;
  int k = b >> 9;               // 512 blocks per k, 8 rows each
  int i0 = (b & 511) * 8;
  __shared__ float mi[Ss][Ss+1];
  __shared__ float zs[8][Ss];
  for (int t = threadIdx.x; t < Ss*Ss; t += 256) mi[t>>5][t&31] = Minv[(size_t)k*Ss*Ss + t];
  { int t = threadIdx.x; zs[t>>5][t&31] = Zt[((size_t)k*Nn + i0)*Ss + t]; }
  __syncthreads();
  int s = threadIdx.x & 31, ii = threadIdx.x >> 5;
  float acc = 0.f;
  #pragma unroll
  for (int s2 = 0; s2 < Ss; s2++) acc += mi[s][s2] * zs[ii][s2];
  MZt[((size_t)k*Nn + i0 + ii)*Ss + s] = acc;
}

// ---------------- main: sparse scores -> softmax -> v -> H_agg row ----------------
__global__ __launch_bounds__(256) void agg_kernel(const float* __restrict__ Zt,
                                                  const float* __restrict__ MZt,
                                                  const float* __restrict__ U,
                                                  const float* __restrict__ wvec,
                                                  const int* __restrict__ rowp,
                                                  const int* __restrict__ colx,
                                                  float* __restrict__ Hagg){
  int i = blockIdx.x;
  int tid = threadIdx.x;
  int lane = tid & 63, wave = tid >> 6;
  __shared__ __align__(16) float zi[Ss];
  __shared__ float sc[1024];
  __shared__ int   cols[1024];
  __shared__ float vred[8][Ss];
  __shared__ __align__(16) float vsh[Ss];
  __shared__ float red[4];
  __shared__ float s_max, s_sum;

  int beg = rowp[i];
  int m = rowp[i+1] - beg;
  if (m > 1024) m = 1024;   // statistically impossible; memory-safety only
  for (int t = tid; t < m; t += 256) cols[t] = colx[beg + t];

  float aggd = 0.f;
  #pragma unroll 1
  for (int k = 0; k < Kk; k++){
    __syncthreads();
    if (tid < Ss) zi[tid] = Zt[((size_t)k*Nn + i)*Ss + tid];
    __syncthreads();
    // scores over neighbors
    float lmax = -3.0e38f;
    for (int t = tid; t < m; t += 256){
      int j = cols[t];
      const float4* mzp = (const float4*)(MZt + ((size_t)k*Nn + j)*Ss);
      float acc = 0.f;
      #pragma unroll
      for (int q = 0; q < 8; q++){
        float4 z4 = ((const float4*)zi)[q];
        float4 mz = mzp[q];
        acc += z4.x*mz.x + z4.y*mz.y + z4.z*mz.z + z4.w*mz.w;
      }
      sc[t] = acc;
      lmax = fmaxf(lmax, acc);
    }
    lmax = waveReduceMax(lmax);
    if (lane == 0) red[wave] = lmax;
    __syncthreads();
    if (tid == 0) s_max = fmaxf(fmaxf(red[0],red[1]), fmaxf(red[2],red[3]));
    __syncthreads();
    float mm = s_max;
    float lsum = 0.f;
    for (int t = tid; t < m; t += 256){
      float e = __expf(sc[t] - mm);
      sc[t] = e;
      lsum += e;
    }
    lsum = waveReduceSum(lsum);
    __syncthreads();
    if (lane == 0) red[wave] = lsum;
    __syncthreads();
    if (tid == 0) s_sum = red[0]+red[1]+red[2]+red[3];
    __syncthreads();
    float rinv = 1.0f / s_sum;
    // v[s] = (sum_j e_j * MZt[j][s]) * rinv
    int s = tid & 31, grp = tid >> 5;
    float part = 0.f;
    for (int t = grp; t < m; t += 8){
      part += sc[t] * MZt[((size_t)k*Nn + cols[t])*Ss + s];
    }
    vred[grp][s] = part;
    __syncthreads();
    if (tid < Ss){
      float vv = 0.f;
      #pragma unroll
      for (int g2 = 0; g2 < 8; g2++) vv += vred[g2][tid];
      vsh[tid] = vv * rinv;
    }
    __syncthreads();
    // grad row: d = tid, aggd += w_k * sum_s Uk[d][s]*v[s]
    const float4* up = (const float4*)(U + (size_t)k*Dd*Ss + (size_t)tid*Ss);
    float gacc = 0.f;
    #pragma unroll
    for (int q = 0; q < 8; q++){
      float4 u4 = up[q];
      float4 v4 = ((const float4*)vsh)[q];
      gacc += u4.x*v4.x + u4.y*v4.y + u4.z*v4.z + u4.w*v4.w;
    }
    aggd += wvec[k] * gacc;
  }
  Hagg[(size_t)i*Dd + tid] = aggd;
}

// ---------------- H_half -> soft-threshold -> H_out (fuses L @ H_agg sparsely) ----------------
__global__ __launch_bounds__(256) void hout_kernel(const float* __restrict__ hops0,
                                                   const float* __restrict__ Hagg,
                                                   const float* __restrict__ thr,
                                                   const float* __restrict__ lambda_ptr,
                                                   const int* __restrict__ rowp,
                                                   const int* __restrict__ colx,
                                                   float* __restrict__ out){
  int i = blockIdx.x, d = threadIdx.x;
  __shared__ int cols[1024];
  int beg = rowp[i];
  int m = rowp[i+1] - beg; if (m > 1024) m = 1024;
  for (int t = d; t < m; t += 256) cols[t] = colx[beg + t];
  __syncthreads();
  float nb = 0.f;
  for (int t = 0; t < m; t++) nb += Hagg[(size_t)cols[t]*Dd + d];
  float hi  = Hagg[(size_t)i*Dd + d];
  float lam = lambda_ptr[0];
  float lap = lam * ((float)m * hi - nb);      // deg_i == m (A entries are 1.0, diag incl.)
  float h = hops0[(size_t)i*Dd + d] + kEta*hi - kEta*lap;
  float a = fabsf(h) - thr[d];
  float r = (a > 0.f) ? a : 0.f;
  out[(size_t)i*Dd + d] = copysignf(r, h);
}

// ---------------- lap_smooth = sum H_out * (L @ H_out) ----------------
__global__ __launch_bounds__(256) void lap_kernel(const float* __restrict__ Hout,
                                                  const int* __restrict__ rowp,
                                                  const int* __restrict__ colx,
                                                  float* __restrict__ lap_out){
  int i = blockIdx.x, d = threadIdx.x;
  __shared__ int cols[1024];
  int beg = rowp[i];
  int m = rowp[i+1] - beg; if (m > 1024) m = 1024;
  for (int t = d; t < m; t += 256) cols[t] = colx[beg + t];
  __syncthreads();
  float nb = 0.f;
  for (int t = 0; t < m; t++) nb += Hout[(size_t)cols[t]*Dd + d];
  float hi = Hout[(size_t)i*Dd + d];
  float val = hi * ((float)m * hi - nb);
  val = waveReduceSum(val);
  __shared__ float red[4];
  if ((d & 63) == 0) red[d >> 6] = val;
  __syncthreads();
  if (d == 0) atomicAdd(lap_out, red[0]+red[1]+red[2]+red[3]);
}

// ---------------- orth_loss ----------------
__global__ __launch_bounds__(256) void orth_kernel(const float* __restrict__ U,
                                                   float* __restrict__ orth_out){
  int g = blockIdx.x*256 + threadIdx.x;   // 0..10239
  int pair = g >> 10;
  int idx = g & 1023;
  int s1 = idx >> 5, s2 = idx & 31;
  const int pk_[10] = {0,0,0,0,1,1,1,2,2,3};
  const int pl_[10] = {0,1,2,3,1,2,3,2,3,3};
  int pk = pk_[pair], pl = pl_[pair];
  const float* Uk = U + (size_t)pk*Dd*Ss;
  const float* Ul = U + (size_t)pl*Dd*Ss;
  float dot = 0.f;
  for (int d = 0; d < Dd; d++) dot += Uk[d*Ss + s1] * Ul[d*Ss + s2];
  float val = dot - ((pk == pl && s1 == s2) ? 1.f : 0.f);
  val *= val;
  val = waveReduceSum(val);
  __shared__ float red[4];
  if ((threadIdx.x & 63) == 0) red[threadIdx.x >> 6] = val;
  __syncthreads();
  if (threadIdx.x == 0) atomicAdd(orth_out, red[0]+red[1]+red[2]+red[3]);
}

// ---------------- launch ----------------
extern "C" void kernel_launch(void* const* d_in, const int* in_sizes, int n_in,
                              void* d_out, int out_size, void* d_ws, size_t ws_size,
                              hipStream_t stream)
{
  const float* hops = (const float*)d_in[0];   // (K,N,D)
  const float* A    = (const float*)d_in[1];   // (N,N)
  const float* L    = (const float*)d_in[2];   // unused: L applied sparsely via A's CSR
  const float* U    = (const float*)d_in[3];   // (K,D,S)
  const float* hw   = (const float*)d_in[4];   // (K,)
  const float* thr  = (const float*)d_in[5];   // (D,)
  const float* lam  = (const float*)d_in[6];   // scalar
  (void)L; (void)in_sizes; (void)n_in; (void)out_size; (void)ws_size;

  float* out = (float*)d_out;
  float* ws  = (float*)d_ws;

  // workspace layout (float offsets)
  float* Z    = ws;                 // K*S*N = 524288
  float* Zt   = ws + 524288;        // K*N*S = 524288
  float* MZt  = ws + 1048576;       // K*N*S = 524288
  float* Mm   = ws + 1572864;       // K*S*S = 4096
  float* Minv = ws + 1576960;       // 4096
  float* Hagg = ws + 1581056;       // N*D = 1048576
  int*   rowp = (int*)(ws + 2629632);   // N+1
  int*   cnt  = (int*)(ws + 2633736);   // N
  int*   colx = (int*)(ws + 2637832);   // capacity 786432 (expected nnz ~ 340K)

  float* orth_out = out + 1048576;
  float* lap_out  = out + 1048577;
  float* w_out    = out + 1048578;

  init_kernel<<<1, 64, 0, stream>>>(hw, out);
  cnt_kernel <<<Nn, 256, 0, stream>>>(A, cnt);
  scan_kernel<<<1, 1024, 0, stream>>>(cnt, rowp);
  fill_kernel<<<Nn, 256, 0, stream>>>(A, rowp, colx);
  z_kernel   <<<Kk*256, 256, 0, stream>>>(hops, U, Z, Zt);
  m_kernel   <<<Kk*1024, 256, 0, stream>>>(Z, Mm);
  inv_kernel <<<Kk, dim3(32,32), 0, stream>>>(Mm, Minv);
  mz_kernel  <<<Kk*512, 256, 0, stream>>>(Zt, Minv, MZt);
  agg_kernel <<<Nn, 256, 0, stream>>>(Zt, MZt, U, w_out, rowp, colx, Hagg);
  hout_kernel<<<Nn, 256, 0, stream>>>(hops, Hagg, thr, lam, rowp, colx, out);
  lap_kernel <<<Nn, 256, 0, stream>>>(out, rowp, colx, lap_out);
  orth_kernel<<<40, 256, 0, stream>>>(U, orth_out);
}

// Round 2
// 387.234 us; speedup vs baseline: 1.1378x; 1.1378x over previous
//
#include <hip/hip_runtime.h>
#include <cstddef>

static constexpr int Nn = 4096;
static constexpr int Dd = 256;
static constexpr int Ss = 32;
static constexpr int Kk = 4;
static constexpr int CAP = 256;          // max neighbors/row (mean ~82, max ~120)
static constexpr float kEta   = 0.5f;
static constexpr float kCoeff = 0.03125f; // S/(N*EPS^2)

// ---------------- reduction helpers ----------------
__device__ __forceinline__ float waveReduceSum(float v){
  #pragma unroll
  for (int off = 32; off > 0; off >>= 1) v += __shfl_down(v, off, 64);
  return v;
}

// ---------------- init: zero scalar slots, w = softmax(hop_weights) ----------------
__global__ void init_kernel(const float* __restrict__ hw, float* __restrict__ out){
  if (threadIdx.x == 0){
    out[1048576] = 0.f;   // orth_loss
    out[1048577] = 0.f;   // lap_smooth
    float a0=hw[0], a1=hw[1], a2=hw[2], a3=hw[3];
    float m = fmaxf(fmaxf(a0,a1), fmaxf(a2,a3));
    float e0=expf(a0-m), e1=expf(a1-m), e2=expf(a2-m), e3=expf(a3-m);
    float s = e0+e1+e2+e3;
    out[1048578]=e0/s; out[1048579]=e1/s; out[1048580]=e2/s; out[1048581]=e3/s;
  }
}

// ---------------- single-pass CSR build: fixed stride CAP, shfl-scan compaction ----------------
__global__ __launch_bounds__(256) void build_kernel(const float* __restrict__ A,
                                                    int* __restrict__ deg,
                                                    int* __restrict__ colx){
  int i = blockIdx.x, tid = threadIdx.x;
  int lane = tid & 63, wave = tid >> 6;
  __shared__ int wcnt[4];
  const float4* row4 = (const float4*)(A + (size_t)i * Nn);
  int* outc = colx + (size_t)i * CAP;
  int rbase = 0;
  for (int c0 = 0; c0 < 1024; c0 += 256){
    int c = c0 + tid;
    float4 v = row4[c];
    int f0 = (v.x != 0.f), f1 = (v.y != 0.f), f2 = (v.z != 0.f), f3 = (v.w != 0.f);
    int nf = f0 + f1 + f2 + f3;
    int inc = nf;
    #pragma unroll
    for (int off = 1; off < 64; off <<= 1){
      int o = __shfl_up(inc, off, 64);
      if (lane >= off) inc += o;
    }
    if (lane == 63) wcnt[wave] = inc;
    __syncthreads();
    int wb = 0;
    for (int w = 0; w < wave; w++) wb += wcnt[w];
    int tot = wcnt[0] + wcnt[1] + wcnt[2] + wcnt[3];
    int pos = rbase + wb + inc - nf;
    int j0 = c * 4;
    if (f0){ if (pos < CAP) outc[pos] = j0;     pos++; }
    if (f1){ if (pos < CAP) outc[pos] = j0 + 1; pos++; }
    if (f2){ if (pos < CAP) outc[pos] = j0 + 2; pos++; }
    if (f3){ if (pos < CAP) outc[pos] = j0 + 3; pos++; }
    rbase += tot;
    __syncthreads();
  }
  if (tid == 0) deg[i] = (rbase < CAP) ? rbase : CAP;
}

// ---------------- Zt4[i][k*32+s] = dot(hops[k][i][:], U[k][:,s]) ----------------
__global__ __launch_bounds__(256) void z_kernel(const float* __restrict__ hops,
                                                const float* __restrict__ U,
                                                float* __restrict__ Zt4){
  int b = blockIdx.x;
  int k = b >> 9;
  int i0 = (b & 511) * 8;
  __shared__ float Us[Ss][260];        // transposed U_k, padded (260*4B=1040B, 16B-aligned rows)
  for (int t = threadIdx.x; t < Dd * Ss; t += 256){
    int s = t & 31, d = t >> 5;
    Us[s][d] = U[(size_t)k * Dd * Ss + t];
  }
  __syncthreads();
  int s = threadIdx.x & 31, ii = threadIdx.x >> 5;
  int i = i0 + ii;
  const float4* h4 = (const float4*)(hops + ((size_t)k * Nn + i) * Dd);
  const float4* u4 = (const float4*)(&Us[s][0]);
  float acc = 0.f;
  #pragma unroll 8
  for (int dq = 0; dq < 64; dq++){
    float4 h = h4[dq];
    float4 u = u4[dq];
    acc += h.x*u.x + h.y*u.y + h.z*u.z + h.w*u.w;
  }
  Zt4[(size_t)i * 128 + k * 32 + s] = acc;
}

// ---------------- partial Z Z^T: 64 row-chunks of 64 per k ----------------
__global__ __launch_bounds__(256) void mpart_kernel(const float* __restrict__ Zt4,
                                                    float* __restrict__ Mpart){
  int b = blockIdx.x;                 // k*64 + ch
  int k = b >> 6, ch = b & 63;
  int i0 = ch * 64;
  __shared__ float zs[64][33];
  for (int t = threadIdx.x; t < 64 * 32; t += 256){
    int ii = t >> 5, s = t & 31;
    zs[ii][s] = Zt4[(size_t)(i0 + ii) * 128 + k * 32 + s];
  }
  __syncthreads();
  int tid = threadIdx.x;
  float acc[4] = {0.f, 0.f, 0.f, 0.f};
  for (int ii = 0; ii < 64; ii++){
    #pragma unroll
    for (int q = 0; q < 4; q++){
      int p = q * 256 + tid;
      acc[q] += zs[ii][p >> 5] * zs[ii][p & 31];
    }
  }
  float* outp = Mpart + (size_t)b * 1024;
  #pragma unroll
  for (int q = 0; q < 4; q++) outp[q * 256 + tid] = acc[q];
}

// ---------------- 32x32 SPD inverse (Gauss-Jordan), folds coeff & +I at load ----------------
__global__ __launch_bounds__(1024) void inv_kernel(const float* __restrict__ Mpart,
                                                   float* __restrict__ Minv){
  int k = blockIdx.x;
  int c = threadIdx.x, r = threadIdx.y;
  __shared__ float a[32][65];
  __shared__ float piv;
  __shared__ float fcol[32];
  float ssum = 0.f;
  for (int ch = 0; ch < 64; ch++)
    ssum += Mpart[((size_t)(k * 64 + ch)) * 1024 + r * 32 + c];
  a[r][c]      = kCoeff * ssum + ((r == c) ? 1.f : 0.f);
  a[r][32 + c] = (r == c) ? 1.f : 0.f;
  for (int p = 0; p < 32; p++){
    __syncthreads();
    if (c == 0 && r == 0) piv = 1.f / a[p][p];
    __syncthreads();
    if (r == p){ a[p][c] *= piv; a[p][32+c] *= piv; }
    __syncthreads();
    if (c == 0) fcol[r] = a[r][p];
    __syncthreads();
    if (r != p){
      float f = fcol[r];
      a[r][c]    -= f * a[p][c];
      a[r][32+c] -= f * a[p][32+c];
    }
  }
  __syncthreads();
  Minv[((size_t)k * Ss + r) * Ss + c] = a[r][32 + c];
}

// ---------------- MZt4[i][k*32+s] = sum_s2 Minv[k][s][s2] * Zt4[i][k*32+s2] ----------------
__global__ __launch_bounds__(256) void mz_kernel(const float* __restrict__ Zt4,
                                                 const float* __restrict__ Minv,
                                                 float* __restrict__ MZt4){
  int b = blockIdx.x;                 // k*128 + chunk(32 rows)
  int k = b >> 7;
  int i0 = (b & 127) * 32;
  __shared__ float mi[32][33];
  __shared__ float zs[32][33];
  for (int t = threadIdx.x; t < 1024; t += 256){
    int ii = t >> 5, s2 = t & 31;
    mi[ii][s2] = Minv[(size_t)k * 1024 + t];
    zs[ii][s2] = Zt4[(size_t)(i0 + ii) * 128 + k * 32 + s2];
  }
  __syncthreads();
  int s = threadIdx.x & 31;
  for (int rr = 0; rr < 4; rr++){
    int ii = rr * 8 + (threadIdx.x >> 5);
    float acc = 0.f;
    #pragma unroll
    for (int s2 = 0; s2 < 32; s2++) acc += mi[s][s2] * zs[ii][s2];
    MZt4[(size_t)(i0 + ii) * 128 + k * 32 + s] = acc;
  }
}

// ---------------- main: all-k sparse scores -> softmax -> v -> H_agg row ----------------
__global__ __launch_bounds__(256) void agg_kernel(const float* __restrict__ Zt4,
                                                  const float* __restrict__ MZt4,
                                                  const float* __restrict__ U,
                                                  const float* __restrict__ wvec,
                                                  const int* __restrict__ deg,
                                                  const int* __restrict__ colx,
                                                  float* __restrict__ Hagg){
  int i = blockIdx.x, tid = threadIdx.x;
  int lane = tid & 63, wave = tid >> 6;
  __shared__ int cols[CAP];
  __shared__ __align__(16) float zi[128];
  __shared__ float sc[4 * 264];                 // stride 264: bank-spread for 4-k reads
  __shared__ __align__(16) float vred[8][132];
  __shared__ __align__(16) float vsh[128];
  __shared__ float red[4][4];
  __shared__ float smax[4];
  __shared__ float rinvw[4];
  __shared__ float wl[4];

  int m = deg[i];
  if (tid < 128) zi[tid] = Zt4[(size_t)i * 128 + tid];
  if (tid < 4) wl[tid] = wvec[tid];
  for (int t = tid; t < m; t += 256) cols[t] = colx[(size_t)i * CAP + t];
  __syncthreads();

  // ---- phase A: scores for all 4 k, 8 lanes cooperate per neighbor (coalesced 512B rows)
  {
    int grp = tid >> 3, q = tid & 7;
    const float4* zi4 = (const float4*)zi;
    for (int t0 = 0; t0 < m; t0 += 32){
      int t = t0 + grp;
      float p0 = 0.f, p1 = 0.f, p2 = 0.f, p3 = 0.f;
      if (t < m){
        int j = cols[t];
        const float4* r4 = (const float4*)(MZt4 + (size_t)j * 128);
        float4 a0 = r4[q],      z0 = zi4[q];
        float4 a1 = r4[8 + q],  z1 = zi4[8 + q];
        float4 a2 = r4[16 + q], z2 = zi4[16 + q];
        float4 a3 = r4[24 + q], z3 = zi4[24 + q];
        p0 = a0.x*z0.x + a0.y*z0.y + a0.z*z0.z + a0.w*z0.w;
        p1 = a1.x*z1.x + a1.y*z1.y + a1.z*z1.z + a1.w*z1.w;
        p2 = a2.x*z2.x + a2.y*z2.y + a2.z*z2.z + a2.w*z2.w;
        p3 = a3.x*z3.x + a3.y*z3.y + a3.z*z3.z + a3.w*z3.w;
      }
      #pragma unroll
      for (int off = 4; off > 0; off >>= 1){
        p0 += __shfl_down(p0, off, 64);
        p1 += __shfl_down(p1, off, 64);
        p2 += __shfl_down(p2, off, 64);
        p3 += __shfl_down(p3, off, 64);
      }
      if (q == 0 && t < m){
        sc[0*264 + t] = p0; sc[1*264 + t] = p1;
        sc[2*264 + t] = p2; sc[3*264 + t] = p3;
      }
    }
  }
  __syncthreads();

  // ---- softmax for all 4 k simultaneously
  {
    float v0=-3.0e38f, v1=-3.0e38f, v2=-3.0e38f, v3=-3.0e38f;
    if (tid < m){
      v0 = sc[0*264 + tid]; v1 = sc[1*264 + tid];
      v2 = sc[2*264 + tid]; v3 = sc[3*264 + tid];
    }
    #pragma unroll
    for (int off = 32; off > 0; off >>= 1){
      v0 = fmaxf(v0, __shfl_down(v0, off, 64));
      v1 = fmaxf(v1, __shfl_down(v1, off, 64));
      v2 = fmaxf(v2, __shfl_down(v2, off, 64));
      v3 = fmaxf(v3, __shfl_down(v3, off, 64));
    }
    if (lane == 0){ red[wave][0]=v0; red[wave][1]=v1; red[wave][2]=v2; red[wave][3]=v3; }
    __syncthreads();
    if (tid < 4)
      smax[tid] = fmaxf(fmaxf(red[0][tid], red[1][tid]), fmaxf(red[2][tid], red[3][tid]));
    __syncthreads();
    float e0=0.f, e1=0.f, e2=0.f, e3=0.f;
    if (tid < m){
      e0 = __expf(sc[0*264 + tid] - smax[0]);
      e1 = __expf(sc[1*264 + tid] - smax[1]);
      e2 = __expf(sc[2*264 + tid] - smax[2]);
      e3 = __expf(sc[3*264 + tid] - smax[3]);
      sc[0*264 + tid] = e0; sc[1*264 + tid] = e1;
      sc[2*264 + tid] = e2; sc[3*264 + tid] = e3;
    }
    float s0=e0, s1=e1, s2=e2, s3=e3;
    #pragma unroll
    for (int off = 32; off > 0; off >>= 1){
      s0 += __shfl_down(s0, off, 64);
      s1 += __shfl_down(s1, off, 64);
      s2 += __shfl_down(s2, off, 64);
      s3 += __shfl_down(s3, off, 64);
    }
    if (lane == 0){ red[wave][0]=s0; red[wave][1]=s1; red[wave][2]=s2; red[wave][3]=s3; }
    __syncthreads();
    if (tid < 4){
      float ss = red[0][tid] + red[1][tid] + red[2][tid] + red[3][tid];
      rinvw[tid] = wl[tid] / ss;      // fold hop weight into normalization
    }
    __syncthreads();
  }

  // ---- phase B: v[c] = sum_j alpha_j * MZt4[j][c]  (32 lanes per neighbor, coalesced)
  {
    int g = tid >> 5, s = tid & 31;
    int ksel = s >> 3;
    float4 part = make_float4(0.f, 0.f, 0.f, 0.f);
    for (int t = g; t < m; t += 8){
      int j = cols[t];
      float4 a = ((const float4*)(MZt4 + (size_t)j * 128))[s];
      float e = sc[ksel * 264 + t];
      part.x += e * a.x; part.y += e * a.y; part.z += e * a.z; part.w += e * a.w;
    }
    ((float4*)&vred[g][0])[s] = part;
  }
  __syncthreads();
  if (tid < 128){
    float vv = 0.f;
    #pragma unroll
    for (int g = 0; g < 8; g++) vv += vred[g][tid];
    vsh[tid] = vv * rinvw[tid >> 5];
  }
  __syncthreads();

  // ---- phase C: H_agg[i][d] = sum_k sum_s U[k][d][s] * vsh[k*32+s]
  {
    float facc = 0.f;
    const float4* v4 = (const float4*)vsh;
    #pragma unroll
    for (int k = 0; k < 4; k++){
      const float4* u4 = (const float4*)(U + (size_t)k * Dd * Ss + (size_t)tid * Ss);
      #pragma unroll
      for (int qq = 0; qq < 8; qq++){
        float4 u = u4[qq];
        float4 v = v4[k * 8 + qq];
        facc += u.x*v.x + u.y*v.y + u.z*v.z + u.w*v.w;
      }
    }
    Hagg[(size_t)i * Dd + tid] = facc;
  }
}

// ---------------- H_half -> soft-threshold -> H_out (sparse L apply) ----------------
__global__ __launch_bounds__(256) void hout_kernel(const float* __restrict__ hops0,
                                                   const float* __restrict__ Hagg,
                                                   const float* __restrict__ thr,
                                                   const float* __restrict__ lambda_ptr,
                                                   const int* __restrict__ deg,
                                                   const int* __restrict__ colx,
                                                   float* __restrict__ out){
  int i = blockIdx.x, d = threadIdx.x;
  __shared__ int cols[CAP];
  int m = deg[i];
  for (int t = d; t < m; t += 256) cols[t] = colx[(size_t)i * CAP + t];
  __syncthreads();
  float nb = 0.f;
  #pragma unroll 4
  for (int t = 0; t < m; t++) nb += Hagg[(size_t)cols[t] * Dd + d];
  float hi  = Hagg[(size_t)i * Dd + d];
  float lam = lambda_ptr[0];
  float lap = lam * ((float)m * hi - nb);      // deg_i == m
  float h = hops0[(size_t)i * Dd + d] + kEta * hi - kEta * lap;
  float a = fabsf(h) - thr[d];
  float r = (a > 0.f) ? a : 0.f;
  out[(size_t)i * Dd + d] = copysignf(r, h);
}

// ---------------- lap_smooth = sum H_out * (L @ H_out) ----------------
__global__ __launch_bounds__(256) void lap_kernel(const float* __restrict__ Hout,
                                                  const int* __restrict__ deg,
                                                  const int* __restrict__ colx,
                                                  float* __restrict__ lap_out){
  int i = blockIdx.x, d = threadIdx.x;
  __shared__ int cols[CAP];
  int m = deg[i];
  for (int t = d; t < m; t += 256) cols[t] = colx[(size_t)i * CAP + t];
  __syncthreads();
  float nb = 0.f;
  #pragma unroll 4
  for (int t = 0; t < m; t++) nb += Hout[(size_t)cols[t] * Dd + d];
  float hi = Hout[(size_t)i * Dd + d];
  float val = hi * ((float)m * hi - nb);
  val = waveReduceSum(val);
  __shared__ float red[4];
  if ((d & 63) == 0) red[d >> 6] = val;
  __syncthreads();
  if (d == 0) atomicAdd(lap_out, red[0] + red[1] + red[2] + red[3]);
}

// ---------------- orth_loss ----------------
__global__ __launch_bounds__(256) void orth_kernel(const float* __restrict__ U,
                                                   float* __restrict__ orth_out){
  int g = blockIdx.x * 256 + threadIdx.x;   // 0..10239
  int pair = g >> 10;
  int idx = g & 1023;
  int s1 = idx >> 5, s2 = idx & 31;
  const int pk_[10] = {0,0,0,0,1,1,1,2,2,3};
  const int pl_[10] = {0,1,2,3,1,2,3,2,3,3};
  int pk = pk_[pair], pl = pl_[pair];
  const float* Uk = U + (size_t)pk * Dd * Ss;
  const float* Ul = U + (size_t)pl * Dd * Ss;
  float dot = 0.f;
  for (int d = 0; d < Dd; d++) dot += Uk[d * Ss + s1] * Ul[d * Ss + s2];
  float val = dot - ((pk == pl && s1 == s2) ? 1.f : 0.f);
  val *= val;
  val = waveReduceSum(val);
  __shared__ float red[4];
  if ((threadIdx.x & 63) == 0) red[threadIdx.x >> 6] = val;
  __syncthreads();
  if (threadIdx.x == 0) atomicAdd(orth_out, red[0] + red[1] + red[2] + red[3]);
}

// ---------------- launch ----------------
extern "C" void kernel_launch(void* const* d_in, const int* in_sizes, int n_in,
                              void* d_out, int out_size, void* d_ws, size_t ws_size,
                              hipStream_t stream)
{
  const float* hops = (const float*)d_in[0];   // (K,N,D)
  const float* A    = (const float*)d_in[1];   // (N,N)
  const float* L    = (const float*)d_in[2];   // unused: applied sparsely via CSR
  const float* U    = (const float*)d_in[3];   // (K,D,S)
  const float* hw   = (const float*)d_in[4];   // (K,)
  const float* thr  = (const float*)d_in[5];   // (D,)
  const float* lam  = (const float*)d_in[6];   // scalar
  (void)L; (void)in_sizes; (void)n_in; (void)out_size; (void)ws_size;

  float* out = (float*)d_out;
  float* ws  = (float*)d_ws;

  // workspace layout (float offsets)
  float* Zt4   = ws;                    // N*128 = 524288
  float* MZt4  = ws + 524288;           // 524288
  float* Mpart = ws + 1048576;          // K*64*1024 = 262144
  float* Hagg  = ws + 1310720;          // N*D = 1048576
  float* Minv  = ws + 2359296;          // 4096
  int*   deg   = (int*)(ws + 2363392);  // N
  int*   colx  = (int*)(ws + 2367488);  // N*CAP = 1048576

  float* orth_out = out + 1048576;
  float* lap_out  = out + 1048577;
  float* w_out    = out + 1048578;

  init_kernel <<<1, 64, 0, stream>>>(hw, out);
  build_kernel<<<Nn, 256, 0, stream>>>(A, deg, colx);
  z_kernel    <<<Kk*512, 256, 0, stream>>>(hops, U, Zt4);
  mpart_kernel<<<Kk*64, 256, 0, stream>>>(Zt4, Mpart);
  inv_kernel  <<<Kk, dim3(32,32), 0, stream>>>(Mpart, Minv);
  mz_kernel   <<<Kk*128, 256, 0, stream>>>(Zt4, Minv, MZt4);
  agg_kernel  <<<Nn, 256, 0, stream>>>(Zt4, MZt4, U, w_out, deg, colx, Hagg);
  hout_kernel <<<Nn, 256, 0, stream>>>(hops, Hagg, thr, lam, deg, colx, out);
  lap_kernel  <<<Nn, 256, 0, stream>>>(out, deg, colx, lap_out);
  orth_kernel <<<40, 256, 0, stream>>>(U, orth_out);
}